// Round 1
// baseline (828.089 us; speedup 1.0000x reference)
//
#include <hip/hip_runtime.h>

#define NSMP 8192
#define INW  8712   // input row stride (floats)
#define OUTW 8448   // output row stride (floats)
#define AOFF 512    // column offset of A block inside input
#define DO   256    // DOUT

typedef __attribute__((ext_vector_type(8))) short short8;
typedef __attribute__((ext_vector_type(16))) float floatx16;

// pack two fp32 -> two bf16 (truncation; bias ~0.15%*|out| ≈ 0.2 abs, threshold 2.82)
__device__ __forceinline__ unsigned pk_bf16(float lo, float hi) {
    return (__float_as_uint(lo) >> 16) | (__float_as_uint(hi) & 0xffff0000u);
}

// ---------------- Kernel A: copy A+I to out[:,256:], column sums -> d ----------
__global__ __launch_bounds__(256) void kcopy(const float* __restrict__ in,
                                             float* __restrict__ out,
                                             float* __restrict__ d) {
    const int t  = threadIdx.x;
    const int j0 = blockIdx.x * 1024;   // 8 col tiles of 1024
    const int i0 = blockIdx.y * 128;    // 64 row tiles of 128
    const int jc = j0 + 4 * t;
    const float* src = in  + (size_t)i0 * INW  + AOFF + jc;
    float*       dst = out + (size_t)i0 * OUTW + DO   + jc;
    float4 cs = make_float4(0.f, 0.f, 0.f, 0.f);
#pragma unroll 8
    for (int r = 0; r < 128; ++r) {
        float4 v = *(const float4*)(src + (size_t)r * INW);
        int di = (i0 + r) - j0;                       // diagonal col within tile
        if ((di >> 2) == t) {                         // di<0 -> negative >> stays negative
            int s = di & 3;
            v.x += (s == 0); v.y += (s == 1); v.z += (s == 2); v.w += (s == 3);
        }
        cs.x += v.x; cs.y += v.y; cs.z += v.z; cs.w += v.w;
        *(float4*)(dst + (size_t)r * OUTW) = v;
    }
    atomicAdd(&d[jc + 0], cs.x);
    atomicAdd(&d[jc + 1], cs.y);
    atomicAdd(&d[jc + 2], cs.z);
    atomicAdd(&d[jc + 3], cs.w);
}

// ------- Kernel B: support = X@W, s'T[c][j] = bf16(rsqrt(d_j)*support[j][c]) ----
__global__ __launch_bounds__(256) void ksupport(const float* __restrict__ in,
                                                const float* __restrict__ w,
                                                const float* __restrict__ d,
                                                float* __restrict__ dinv,
                                                unsigned short* __restrict__ sT) {
    const int c  = threadIdx.x;          // output column 0..255
    const int r0 = blockIdx.x * 8;       // 8 support-rows per block
    const float* X = in + (size_t)r0 * INW;   // X = input[:, :512]
    float acc[8] = {0.f, 0.f, 0.f, 0.f, 0.f, 0.f, 0.f, 0.f};
#pragma unroll 4
    for (int k = 0; k < 512; ++k) {
        float wv = w[(size_t)k * DO + c];
#pragma unroll
        for (int r = 0; r < 8; ++r)
            acc[r] = fmaf(X[(size_t)r * INW + k], wv, acc[r]);  // X load is wave-uniform -> s_load
    }
    union { unsigned short h[8]; uint4 u; } pk;
#pragma unroll
    for (int r = 0; r < 8; ++r) {
        float dv = rsqrtf(d[r0 + r]);
        unsigned ub = __float_as_uint(acc[r] * dv);
        ub += 0x7fffu + ((ub >> 16) & 1u);            // RNE to bf16
        pk.h[r] = (unsigned short)(ub >> 16);
    }
    *(uint4*)(sT + (size_t)c * NSMP + r0) = pk.u;     // transposed store, 16B/lane
    if (c < 8) dinv[r0 + c] = rsqrtf(d[r0 + c]);
}

// ---------------- Kernel C: out[:, :256] = dinv_i * (A0 @ s' + s'_i) -----------
__device__ __forceinline__ floatx16 domfma(const float4& a0, const float4& a1,
                                           const uint4& b, floatx16 acc) {
    union { unsigned u[4]; short8 s; } fa;
    fa.u[0] = pk_bf16(a0.x, a0.y); fa.u[1] = pk_bf16(a0.z, a0.w);
    fa.u[2] = pk_bf16(a1.x, a1.y); fa.u[3] = pk_bf16(a1.z, a1.w);
    union { uint4 q4; short8 s; } fb; fb.q4 = b;
    return __builtin_amdgcn_mfma_f32_32x32x16_bf16(fa.s, fb.s, acc, 0, 0, 0);
}

__global__ __launch_bounds__(256) void kmm(const float* __restrict__ in,
                                           const unsigned short* __restrict__ sT,
                                           const float* __restrict__ dinv,
                                           float* __restrict__ out) {
    const int b  = blockIdx.x;
    // XCD-pair swizzle: blocks b and b+8 (same rg, ch=0/1) land on the same XCD (b%8)
    const int rg = ((b >> 4) << 3) + (b & 7);   // 0..255 row group
    const int ch = (b >> 3) & 1;                // column half
    const int tid = threadIdx.x;
    const int w = tid >> 6, lane = tid & 63;
    const int m = lane & 31, q = lane >> 5;
    const int i0 = rg * 32;
    const int c0 = ch * 128 + w * 32;
    const int cc = c0 + m;
    const float*          Ab = in + (size_t)(i0 + m) * INW + AOFF + q * 8;
    const unsigned short* Bb = sT + (size_t)cc * NSMP + q * 8;

    float4 pa0[16], pa1[16];
    uint4  pb[16];
#pragma unroll
    for (int p = 0; p < 16; ++p) {
        const int k = p * 16;
        pa0[p] = *(const float4*)(Ab + k);
        pa1[p] = *(const float4*)(Ab + k + 4);
        pb[p]  = *(const uint4*)(Bb + k);
    }
    floatx16 acc;
#pragma unroll
    for (int z = 0; z < 16; ++z) acc[z] = 0.f;

#pragma unroll 16
    for (int it = 0; it < 496; ++it) {          // 496 = 31*16
        const int p = it & 15;
        acc = domfma(pa0[p], pa1[p], pb[p], acc);
        const int k = (it + 16) * 16;
        pa0[p] = *(const float4*)(Ab + k);
        pa1[p] = *(const float4*)(Ab + k + 4);
        pb[p]  = *(const uint4*)(Bb + k);
    }
#pragma unroll
    for (int it = 496; it < 512; ++it) {        // drain
        const int p = it & 15;
        acc = domfma(pa0[p], pa1[p], pb[p], acc);
    }

    // epilogue: D row = (reg&3) + 8*(reg>>2) + 4*q, col = lane&31 (HW-verified layout)
    const unsigned short* sCol = sT + (size_t)cc * NSMP + i0 + q * 4;
#pragma unroll
    for (int g = 0; g < 4; ++g) {
        ushort4 s4 = *(const ushort4*)(sCol + 8 * g);
        unsigned short sv[4] = {s4.x, s4.y, s4.z, s4.w};
#pragma unroll
        for (int rr = 0; rr < 4; ++rr) {
            const int row = i0 + 8 * g + 4 * q + rr;
            const float idt = __uint_as_float(((unsigned)sv[rr]) << 16);  // +I contribution, fp32
            out[(size_t)row * OUTW + cc] = (acc[g * 4 + rr] + idt) * dinv[row];
        }
    }
}

extern "C" void kernel_launch(void* const* d_in, const int* in_sizes, int n_in,
                              void* d_out, int out_size, void* d_ws, size_t ws_size,
                              hipStream_t stream) {
    (void)in_sizes; (void)n_in; (void)out_size; (void)ws_size;
    const float* in = (const float*)d_in[0];
    const float* w  = (const float*)d_in[1];
    float* out  = (float*)d_out;
    float* d    = (float*)d_ws;                       // 8192 f32 column sums
    float* dinv = d + NSMP;                           // 8192 f32
    unsigned short* sT = (unsigned short*)(d + 2 * NSMP);  // 256 x 8192 bf16 (4 MB)

    hipMemsetAsync(d, 0, NSMP * sizeof(float), stream);
    kcopy<<<dim3(8, 64), 256, 0, stream>>>(in, out, d);
    ksupport<<<1024, 256, 0, stream>>>(in, w, d, dinv, sT);
    kmm<<<512, 256, 0, stream>>>(in, sT, dinv, out);
}